// Round 1
// baseline (112.269 us; speedup 1.0000x reference)
//
#include <hip/hip_runtime.h>

#define SEQ 512
#define BZ  64
#define DIN 1024
#define HID 256
#define DOUT 1024
#define NLANG 16

typedef __attribute__((ext_vector_type(8))) __bf16 bf16x8;
typedef __attribute__((ext_vector_type(4))) float f32x4;

__device__ __forceinline__ unsigned int f2bf_pack(float lo, float hi) {
    unsigned short a = __builtin_bit_cast(unsigned short, (__bf16)lo);
    unsigned short b = __builtin_bit_cast(unsigned short, (__bf16)hi);
    return (unsigned int)a | ((unsigned int)b << 16);
}

// Transpose+convert: src f32 [L][R][C] -> dst bf16 [L][C][R].
// grid = (L, R/64, C/64), block = 256.
__global__ __launch_bounds__(256)
void transpose_cvt(const float* __restrict__ src, unsigned short* __restrict__ dst,
                   int R, int C) {
    __shared__ float tile[64][65];
    const int l  = blockIdx.x;
    const int rb = blockIdx.y * 64;
    const int cb = blockIdx.z * 64;
    const float* s = src + (long)l * R * C;
    unsigned short* d = dst + (long)l * R * C;
    const int t = threadIdx.x;
#pragma unroll
    for (int j = 0; j < 4; ++j) {
        int u = t + 256 * j;            // 1024 float4 units in a 64x64 f32 tile
        int r = u >> 4, c4 = u & 15;
        float4 v = *(const float4*)(s + (long)(rb + r) * C + cb + c4 * 4);
        tile[r][c4 * 4 + 0] = v.x; tile[r][c4 * 4 + 1] = v.y;
        tile[r][c4 * 4 + 2] = v.z; tile[r][c4 * 4 + 3] = v.w;
    }
    __syncthreads();
#pragma unroll
    for (int j = 0; j < 4; ++j) {
        int u = t + 256 * j;
        int dr = u >> 4, dc4 = u & 15;  // dst row dr (= src col), dst col chunk dc4
        uint2 o;
        o.x = f2bf_pack(tile[dc4 * 4 + 0][dr], tile[dc4 * 4 + 1][dr]);
        o.y = f2bf_pack(tile[dc4 * 4 + 2][dr], tile[dc4 * 4 + 3][dr]);
        *(uint2*)(d + (long)(cb + dr) * R + rb + dc4 * 4) = o;
    }
}

// One GEMM layer:  out[s, n] = act( sum_k A[s, b, k] * Wt[lid, n, k] + bias[lid, n] )
// A tile 64 rows x BK=64, W tile 256 n x 64 k, 4 waves, each wave: 64 rows x 64 cols,
// 4x4 fragments of v_mfma_f32_16x16x32_bf16, fp32 accum.
// grid = (BZ, SEQ/64, NTOT/256), block = 256.
template<int KTOT, int NTOT, bool AF32, bool L1RELU>
__global__ __launch_bounds__(256)
void mlp_gemm(const void* __restrict__ Ap,
              const unsigned short* __restrict__ Wt,   // [NLANG][NTOT][KTOT] bf16 (pre-transposed)
              const float* __restrict__ bias,          // [NLANG][NTOT]
              const int* __restrict__ lang,            // [BZ]
              void* __restrict__ outp) {
    __shared__ uint4 sAq[64 * 64 * 2 / 16];     // 8 KiB  bf16 A tile, swizzled
    __shared__ uint4 sWq[256 * 64 * 2 / 16];    // 32 KiB bf16 W tile, swizzled
    char* sA = (char*)sAq;
    char* sW = (char*)sWq;

    const int b    = blockIdx.x;
    const int st   = blockIdx.y;
    const int nblk = blockIdx.z;
    const int t    = threadIdx.x;
    const int lane = t & 63;
    const int w    = t >> 6;
    const int lid  = lang[b];
    const int s0   = st * 64;

    const float*          Af = (const float*)Ap;
    const unsigned short* Ah = (const unsigned short*)Ap;
    const long Abase = (long)s0 * BZ * KTOT + (long)b * KTOT;   // elem offset of row s0
    const unsigned short* Wbase = Wt + ((long)lid * NTOT + (long)nblk * 256) * KTOT;

    const f32x4 zero4 = {0.f, 0.f, 0.f, 0.f};
    f32x4 acc[4][4];
#pragma unroll
    for (int mi = 0; mi < 4; ++mi)
#pragma unroll
        for (int ni = 0; ni < 4; ++ni) acc[mi][ni] = zero4;

    for (int kt = 0; kt < KTOT / 64; ++kt) {
        // ---- stage A tile [64][64] -> bf16, byte^=((row&7)<<4) swizzle ----
        if constexpr (AF32) {
#pragma unroll
            for (int j = 0; j < 4; ++j) {
                int u = t + 256 * j;
                int m = u >> 4, c4 = u & 15;
                const float4 v = *(const float4*)(Af + Abase + (long)m * (BZ * KTOT) + kt * 64 + c4 * 4);
                uint2 p;
                p.x = f2bf_pack(v.x, v.y);
                p.y = f2bf_pack(v.z, v.w);
                *(uint2*)(sA + (((m * 128) + c4 * 8) ^ ((m & 7) << 4))) = p;
            }
        } else {
#pragma unroll
            for (int j = 0; j < 2; ++j) {
                int u = t + 256 * j;
                int m = u >> 3, c16 = u & 7;
                const uint4 v = *(const uint4*)(Ah + Abase + (long)m * (BZ * KTOT) + kt * 64 + c16 * 8);
                *(uint4*)(sA + (((m * 128) + c16 * 16) ^ ((m & 7) << 4))) = v;
            }
        }
        // ---- stage W tile [256 n][64 k] bf16 ----
#pragma unroll
        for (int j = 0; j < 8; ++j) {
            int u = t + 256 * j;
            int n = u >> 3, c16 = u & 7;
            const uint4 v = *(const uint4*)(Wbase + (long)n * KTOT + kt * 64 + c16 * 8);
            *(uint4*)(sW + (((n * 128) + c16 * 16) ^ ((n & 7) << 4))) = v;
        }
        __syncthreads();

#pragma unroll
        for (int ks = 0; ks < 2; ++ks) {
            const int kb = (ks * 32 + ((lane >> 4) * 8)) * 2;   // byte offset in 128B row
            bf16x8 av[4], bv[4];
#pragma unroll
            for (int mi = 0; mi < 4; ++mi) {
                int r = mi * 16 + (lane & 15);
                av[mi] = __builtin_bit_cast(bf16x8,
                    *(const uint4*)(sA + ((r * 128 + kb) ^ ((r & 7) << 4))));
            }
#pragma unroll
            for (int ni = 0; ni < 4; ++ni) {
                int n = w * 64 + ni * 16 + (lane & 15);
                bv[ni] = __builtin_bit_cast(bf16x8,
                    *(const uint4*)(sW + ((n * 128 + kb) ^ ((n & 7) << 4))));
            }
#pragma unroll
            for (int mi = 0; mi < 4; ++mi)
#pragma unroll
                for (int ni = 0; ni < 4; ++ni)
                    acc[mi][ni] = __builtin_amdgcn_mfma_f32_16x16x32_bf16(
                        av[mi], bv[ni], acc[mi][ni], 0, 0, 0);
        }
        __syncthreads();
    }

    // ---- epilogue: bias (+relu,->bf16) or (->f32) ----
    float bvv[4];
#pragma unroll
    for (int ni = 0; ni < 4; ++ni)
        bvv[ni] = bias[(long)lid * NTOT + nblk * 256 + w * 64 + ni * 16 + (lane & 15)];

#pragma unroll
    for (int mi = 0; mi < 4; ++mi) {
#pragma unroll
        for (int r = 0; r < 4; ++r) {
            const int  row = mi * 16 + (lane >> 4) * 4 + r;
            const long s   = s0 + row;
#pragma unroll
            for (int ni = 0; ni < 4; ++ni) {
                const int col = nblk * 256 + w * 64 + ni * 16 + (lane & 15);
                float v = acc[mi][ni][r] + bvv[ni];
                if constexpr (L1RELU) {
                    v = v > 0.f ? v : 0.f;
                    ((unsigned short*)outp)[(s * BZ + b) * NTOT + col] =
                        __builtin_bit_cast(unsigned short, (__bf16)v);
                } else {
                    ((float*)outp)[(s * BZ + b) * NTOT + col] = v;
                }
            }
        }
    }
}

extern "C" void kernel_launch(void* const* d_in, const int* in_sizes, int n_in,
                              void* d_out, int out_size, void* d_ws, size_t ws_size,
                              hipStream_t stream) {
    const float* x    = (const float*)d_in[0];
    const int*   lang = (const int*)d_in[1];
    const float* W1   = (const float*)d_in[2];
    const float* b1   = (const float*)d_in[3];
    const float* W2   = (const float*)d_in[4];
    const float* b2   = (const float*)d_in[5];
    float* y = (float*)d_out;

    // ws layout: W1t bf16 [16][256][1024] | W2t bf16 [16][1024][256] | h bf16 [512][64][256]
    const size_t w1t_bytes = (size_t)NLANG * HID * DIN * 2;    // 8 MiB
    const size_t w2t_bytes = (size_t)NLANG * DOUT * HID * 2;   // 8 MiB
    unsigned short* W1t = (unsigned short*)d_ws;
    unsigned short* W2t = (unsigned short*)((char*)d_ws + w1t_bytes);
    unsigned short* h   = (unsigned short*)((char*)d_ws + w1t_bytes + w2t_bytes);

    // prep: transpose+convert weights (k-major -> n-major bf16)
    transpose_cvt<<<dim3(NLANG, DIN / 64, HID / 64), 256, 0, stream>>>(W1, W1t, DIN, HID);
    transpose_cvt<<<dim3(NLANG, HID / 64, DOUT / 64), 256, 0, stream>>>(W2, W2t, HID, DOUT);

    // layer 1: h = relu(x @ W1 + b1)   [f32 in, bf16 out]
    mlp_gemm<DIN, HID, true, true>
        <<<dim3(BZ, SEQ / 64, HID / 256), 256, 0, stream>>>(x, W1t, b1, lang, h);

    // layer 2: y = h @ W2 + b2          [bf16 in, f32 out]
    mlp_gemm<HID, DOUT, false, false>
        <<<dim3(BZ, SEQ / 64, DOUT / 256), 256, 0, stream>>>(h, W2t, b2, lang, y);
}